// Round 2
// baseline (2743.921 us; speedup 1.0000x reference)
//
#include <hip/hip_runtime.h>
#include <hip/hip_bf16.h>
#include <math.h>

typedef __hip_bfloat16 bf16;
typedef short bf16x8 __attribute__((ext_vector_type(8)));
typedef float f32x4 __attribute__((ext_vector_type(4)));

static constexpr int S   = 2048;
static constexpr int H   = 1024;
static constexpr int NH  = 16;
static constexpr int NKV = 8;
static constexpr int L   = 2;
static constexpr int CH  = 512;   // MoE token chunk (keeps a13-f32 scratch at 33 MB)

#define ATTN_MULT 0.015625f
#define RES_MULT  0.22f

// split f32 into bf16 hi + bf16 lo (residual); combined mantissa ~17 bits, rel err ~2^-17
__device__ inline void split_bf(float v, bf16& h, bf16& l) {
    h = __float2bfloat16(v);
    l = __float2bfloat16(v - __bfloat162float(h));
}

// ---------------- tiled transpose + f32 -> bf16 (optionally split) ----------------
// out[b][n][k] = in[b][k][n]
template<int SPLIT>
__global__ __launch_bounds__(256) void transpose_cvt(
    const float* __restrict__ in, bf16* __restrict__ oh, bf16* __restrict__ ol,
    int N, long in_bstride, long out_bstride, int out_ld)
{
    __shared__ float tile[32][33];
    int b = blockIdx.z;
    const float* inp = in + (size_t)b * in_bstride;
    int k0 = blockIdx.y * 32, n0 = blockIdx.x * 32;
    int tx = threadIdx.x & 31, ty = threadIdx.x >> 5;
#pragma unroll
    for (int i = 0; i < 4; i++)
        tile[ty + i * 8][tx] = inp[(size_t)(k0 + ty + i * 8) * N + n0 + tx];
    __syncthreads();
#pragma unroll
    for (int i = 0; i < 4; i++) {
        int n = ty + i * 8;
        size_t off = (size_t)b * out_bstride + (size_t)(n0 + n) * out_ld + k0 + tx;
        float v = tile[tx][n];
        if (SPLIT) { bf16 h, l; split_bf(v, h, l); oh[off] = h; ol[off] = l; }
        else oh[off] = __float2bfloat16(v);
    }
}

// ---------------- embedding gather ----------------
__global__ __launch_bounds__(256) void embed_kernel(
    const int* __restrict__ ids, const float* __restrict__ emb, float* __restrict__ h)
{
    int t = blockIdx.x;
    int id = ids[t];
    const float4* src = (const float4*)(emb + (size_t)id * H);
    float4* dst = (float4*)(h + (size_t)t * H);
    float4 v = src[threadIdx.x];
    v.x *= 12.0f; v.y *= 12.0f; v.z *= 12.0f; v.w *= 12.0f;
    dst[threadIdx.x] = v;
}

// ---------------- RMSNorm: MODE 0 = f32 out, 1 = bf16, 2 = split bf16 ----------------
template<int MODE>
__global__ __launch_bounds__(256) void rmsnorm_kernel(
    const float* __restrict__ hbuf, const float* __restrict__ w,
    bf16* __restrict__ oh, bf16* __restrict__ ol, float* __restrict__ of)
{
    int t = blockIdx.x;
    const float4* row = (const float4*)(hbuf + (size_t)t * H);
    float4 v = row[threadIdx.x];
    float ss = v.x * v.x + v.y * v.y + v.z * v.z + v.w * v.w;
#pragma unroll
    for (int off = 32; off > 0; off >>= 1) ss += __shfl_xor(ss, off);
    __shared__ float wsum[4];
    if ((threadIdx.x & 63) == 0) wsum[threadIdx.x >> 6] = ss;
    __syncthreads();
    float tot = wsum[0] + wsum[1] + wsum[2] + wsum[3];
    float rms = rsqrtf(tot * (1.0f / H) + 1e-6f);
    const float4* wp = (const float4*)w;
    float4 wv = wp[threadIdx.x];
    float o[4] = { v.x * rms * wv.x, v.y * rms * wv.y, v.z * rms * wv.z, v.w * rms * wv.w };
    size_t base = (size_t)t * H + threadIdx.x * 4;
    if (MODE == 0) {
#pragma unroll
        for (int j = 0; j < 4; j++) of[base + j] = o[j];
    } else if (MODE == 1) {
#pragma unroll
        for (int j = 0; j < 4; j++) oh[base + j] = __float2bfloat16(o[j]);
    } else {
#pragma unroll
        for (int j = 0; j < 4; j++) { bf16 h, l; split_bf(o[j], h, l); oh[base + j] = h; ol[base + j] = l; }
    }
}

// ---------------- GEMM: C[M,N] = A[M,K] @ Bt[N,K]^T ----------------
// SPLIT: A,B given as hi+lo planes, 3 MFMAs (hh + hl + lh).
// CMODE 0: bf16 store; 1: split bf16 store; 2: f32 store; 3: f32 += (residual)
template<int BM, int BN, int SPLIT, int CMODE>
__global__ __launch_bounds__(256) void gemm_bt(
    const bf16* __restrict__ Ah, const bf16* __restrict__ Al,
    const bf16* __restrict__ Bh, const bf16* __restrict__ Bl,
    void* __restrict__ Ch, bf16* __restrict__ Cl,
    int Kd, int lda, int ldc, float scale)
{
    constexpr int BK = 32, PADE = 40;
    __shared__ __align__(16) bf16 Ash[BM][PADE];
    __shared__ __align__(16) bf16 Bsh[BN][PADE];
    __shared__ __align__(16) bf16 Asl[SPLIT ? BM : 1][PADE];
    __shared__ __align__(16) bf16 Bsl[SPLIT ? BN : 1][PADE];
    int m0 = blockIdx.y * BM, n0 = blockIdx.x * BN;
    int tid = threadIdx.x;
    int wave = tid >> 6, lane = tid & 63;
    int wm = wave >> 1, wn = wave & 1;
    constexpr int WM = BM / 2, WN = BN / 2;
    constexpr int MT = WM / 16, NT = WN / 16;
    int lr = lane & 15, lq = lane >> 4;
    f32x4 acc[MT][NT];
    f32x4 zero = {0.f, 0.f, 0.f, 0.f};
#pragma unroll
    for (int i = 0; i < MT; i++)
#pragma unroll
        for (int j = 0; j < NT; j++) acc[i][j] = zero;

    for (int k0 = 0; k0 < Kd; k0 += BK) {
#pragma unroll
        for (int it = 0; it < BM / 64; it++) {
            int idx = tid + it * 256;
            int r = idx >> 2, c = (idx & 3) * 8;
            *(bf16x8*)&Ash[r][c] = *(const bf16x8*)(Ah + (size_t)(m0 + r) * lda + k0 + c);
            if (SPLIT)
                *(bf16x8*)&Asl[r][c] = *(const bf16x8*)(Al + (size_t)(m0 + r) * lda + k0 + c);
        }
#pragma unroll
        for (int it = 0; it < BN / 64; it++) {
            int idx = tid + it * 256;
            int r = idx >> 2, c = (idx & 3) * 8;
            *(bf16x8*)&Bsh[r][c] = *(const bf16x8*)(Bh + (size_t)(n0 + r) * Kd + k0 + c);
            if (SPLIT)
                *(bf16x8*)&Bsl[r][c] = *(const bf16x8*)(Bl + (size_t)(n0 + r) * Kd + k0 + c);
        }
        __syncthreads();
        bf16x8 ah[MT], bh[NT];
#pragma unroll
        for (int mt = 0; mt < MT; mt++)
            ah[mt] = *(const bf16x8*)&Ash[wm * WM + mt * 16 + lr][lq * 8];
#pragma unroll
        for (int nt = 0; nt < NT; nt++)
            bh[nt] = *(const bf16x8*)&Bsh[wn * WN + nt * 16 + lr][lq * 8];
#pragma unroll
        for (int mt = 0; mt < MT; mt++)
#pragma unroll
            for (int nt = 0; nt < NT; nt++)
                acc[mt][nt] = __builtin_amdgcn_mfma_f32_16x16x32_bf16(ah[mt], bh[nt], acc[mt][nt], 0, 0, 0);
        if (SPLIT) {
            bf16x8 al[MT], bl[NT];
#pragma unroll
            for (int mt = 0; mt < MT; mt++)
                al[mt] = *(const bf16x8*)&Asl[wm * WM + mt * 16 + lr][lq * 8];
#pragma unroll
            for (int nt = 0; nt < NT; nt++)
                bl[nt] = *(const bf16x8*)&Bsl[wn * WN + nt * 16 + lr][lq * 8];
#pragma unroll
            for (int mt = 0; mt < MT; mt++)
#pragma unroll
                for (int nt = 0; nt < NT; nt++) {
                    acc[mt][nt] = __builtin_amdgcn_mfma_f32_16x16x32_bf16(ah[mt], bl[nt], acc[mt][nt], 0, 0, 0);
                    acc[mt][nt] = __builtin_amdgcn_mfma_f32_16x16x32_bf16(al[mt], bh[nt], acc[mt][nt], 0, 0, 0);
                }
        }
        __syncthreads();
    }
#pragma unroll
    for (int mt = 0; mt < MT; mt++)
#pragma unroll
        for (int nt = 0; nt < NT; nt++)
#pragma unroll
            for (int r = 0; r < 4; r++) {
                int m = m0 + wm * WM + mt * 16 + lq * 4 + r;
                int n = n0 + wn * WN + nt * 16 + lr;
                float v = acc[mt][nt][r] * scale;
                size_t off = (size_t)m * ldc + n;
                if (CMODE == 0)      ((bf16*)Ch)[off] = __float2bfloat16(v);
                else if (CMODE == 1) { bf16 h, l; split_bf(v, h, l); ((bf16*)Ch)[off] = h; Cl[off] = l; }
                else if (CMODE == 2) ((float*)Ch)[off] = v;
                else                 ((float*)Ch)[off] += v;
            }
}

// ---------------- RoPE + layout: qkv[S,2048] -> qr[NH,S,64], kr[NKV,S,64], vt[NKV,64,S]
template<int SPLIT>
__global__ __launch_bounds__(256) void rope_kernel(
    const bf16* __restrict__ qkvh, const bf16* __restrict__ qkvl, const int* __restrict__ pos,
    bf16* __restrict__ qr, bf16* __restrict__ kr, bf16* __restrict__ vth, bf16* __restrict__ vtl)
{
    int s = blockIdx.x;
    float p = (float)pos[s];
    int tid = threadIdx.x;
    const bf16* rowh = qkvh + (size_t)s * 2048;
    const bf16* rowl = SPLIT ? qkvl + (size_t)s * 2048 : nullptr;
    auto val = [&](int off) -> float {
        float v = __bfloat162float(rowh[off]);
        if (SPLIT) v += __bfloat162float(rowl[off]);
        return v;
    };
    for (int idx = tid; idx < 512; idx += 256) {  // q: 16 heads x 32 pairs
        int hq = idx >> 5, d = idx & 31;
        float inv = __expf(-(float)d * (9.210340371976184f / 32.0f));
        float sn, cs;
        sincosf(p * inv, &sn, &cs);
        float x1 = val(hq * 64 + d), x2 = val(hq * 64 + d + 32);
        qr[((size_t)hq * S + s) * 64 + d]      = __float2bfloat16(x1 * cs - x2 * sn);
        qr[((size_t)hq * S + s) * 64 + d + 32] = __float2bfloat16(x2 * cs + x1 * sn);
    }
    if (tid < 256) {  // k: 8 heads x 32 pairs
        int hk = tid >> 5, d = tid & 31;
        float inv = __expf(-(float)d * (9.210340371976184f / 32.0f));
        float sn, cs;
        sincosf(p * inv, &sn, &cs);
        float x1 = val(1024 + hk * 64 + d), x2 = val(1024 + hk * 64 + d + 32);
        kr[((size_t)hk * S + s) * 64 + d]      = __float2bfloat16(x1 * cs - x2 * sn);
        kr[((size_t)hk * S + s) * 64 + d + 32] = __float2bfloat16(x2 * cs + x1 * sn);
    }
    for (int idx = tid; idx < 512; idx += 256) {  // v transposed copy (no rope) - copy planes
        int hk = idx >> 6, d = idx & 63;
        vth[((size_t)hk * 64 + d) * S + s] = rowh[1536 + idx];
        if (SPLIT) vtl[((size_t)hk * 64 + d) * S + s] = rowl[1536 + idx];
    }
}

// ---------------- Flash attention: causal, GQA; SPLIT -> P,V split for PV MFMAs ----------------
template<int SPLIT>
__global__ __launch_bounds__(256) void attn_kernel(
    const bf16* __restrict__ qr, const bf16* __restrict__ kr,
    const bf16* __restrict__ vth, const bf16* __restrict__ vtl,
    bf16* __restrict__ oh, bf16* __restrict__ ol)
{
    __shared__ __align__(16) bf16 Psh[4][16][40];
    __shared__ __align__(16) bf16 Psl[SPLIT ? 4 : 1][16][40];
    int wave = threadIdx.x >> 6, lane = threadIdx.x & 63;
    int lr = lane & 15, lq = lane >> 4;
    int h = blockIdx.y, hk = h >> 1;
    int q0 = blockIdx.x * 64 + wave * 16;

    const bf16* qbase = qr + ((size_t)h * S + q0 + lr) * 64 + lq * 8;
    bf16x8 qf0 = *(const bf16x8*)qbase;
    bf16x8 qf1 = *(const bf16x8*)(qbase + 32);

    f32x4 O[4];
    f32x4 zero = {0.f, 0.f, 0.f, 0.f};
#pragma unroll
    for (int db = 0; db < 4; db++) O[db] = zero;
    float mrow[4] = {-1e30f, -1e30f, -1e30f, -1e30f};
    float lrow[4] = {0.f, 0.f, 0.f, 0.f};
    int qmax = q0 + 15;

    for (int k0 = 0; k0 <= qmax; k0 += 32) {
        float sv[2][4];
#pragma unroll
        for (int nb = 0; nb < 2; nb++) {
            const bf16* kbase = kr + ((size_t)hk * S + k0 + nb * 16 + lr) * 64 + lq * 8;
            f32x4 sacc = zero;
            sacc = __builtin_amdgcn_mfma_f32_16x16x32_bf16(qf0, *(const bf16x8*)kbase, sacc, 0, 0, 0);
            sacc = __builtin_amdgcn_mfma_f32_16x16x32_bf16(qf1, *(const bf16x8*)(kbase + 32), sacc, 0, 0, 0);
            int col = k0 + nb * 16 + lr;
#pragma unroll
            for (int r = 0; r < 4; r++) {
                int rowi = q0 + lq * 4 + r;
                sv[nb][r] = (col <= rowi) ? sacc[r] * ATTN_MULT : -1e9f;
            }
        }
        float rm[4];
#pragma unroll
        for (int r = 0; r < 4; r++) rm[r] = fmaxf(sv[0][r], sv[1][r]);
#pragma unroll
        for (int off = 1; off < 16; off <<= 1)
#pragma unroll
            for (int r = 0; r < 4; r++) rm[r] = fmaxf(rm[r], __shfl_xor(rm[r], off));
        float alpha[4], rs[4];
#pragma unroll
        for (int r = 0; r < 4; r++) {
            float mn = fmaxf(mrow[r], rm[r]);
            alpha[r] = __expf(mrow[r] - mn);
            mrow[r] = mn;
            sv[0][r] = __expf(sv[0][r] - mn);
            sv[1][r] = __expf(sv[1][r] - mn);
            rs[r] = sv[0][r] + sv[1][r];
        }
#pragma unroll
        for (int off = 1; off < 16; off <<= 1)
#pragma unroll
            for (int r = 0; r < 4; r++) rs[r] += __shfl_xor(rs[r], off);
#pragma unroll
        for (int r = 0; r < 4; r++) lrow[r] = lrow[r] * alpha[r] + rs[r];
#pragma unroll
        for (int db = 0; db < 4; db++)
#pragma unroll
            for (int r = 0; r < 4; r++) O[db][r] *= alpha[r];
        // P (C-layout) -> LDS -> A-layout, split into hi/lo if SPLIT
#pragma unroll
        for (int nb = 0; nb < 2; nb++)
#pragma unroll
            for (int r = 0; r < 4; r++) {
                if (SPLIT) {
                    bf16 hh, ll; split_bf(sv[nb][r], hh, ll);
                    Psh[wave][lq * 4 + r][nb * 16 + lr] = hh;
                    Psl[wave][lq * 4 + r][nb * 16 + lr] = ll;
                } else {
                    Psh[wave][lq * 4 + r][nb * 16 + lr] = __float2bfloat16(sv[nb][r]);
                }
            }
        __asm volatile("s_waitcnt lgkmcnt(0)" ::: "memory");
        bf16x8 pfh = *(const bf16x8*)&Psh[wave][lr][lq * 8];
        bf16x8 pfl;
        if (SPLIT) pfl = *(const bf16x8*)&Psl[wave][lr][lq * 8];
#pragma unroll
        for (int db = 0; db < 4; db++) {
            size_t vtoff = ((size_t)hk * 64 + db * 16 + lr) * S + k0 + lq * 8;
            bf16x8 vfh = *(const bf16x8*)(vth + vtoff);
            O[db] = __builtin_amdgcn_mfma_f32_16x16x32_bf16(pfh, vfh, O[db], 0, 0, 0);
            if (SPLIT) {
                bf16x8 vfl = *(const bf16x8*)(vtl + vtoff);
                O[db] = __builtin_amdgcn_mfma_f32_16x16x32_bf16(pfh, vfl, O[db], 0, 0, 0);
                O[db] = __builtin_amdgcn_mfma_f32_16x16x32_bf16(pfl, vfh, O[db], 0, 0, 0);
            }
        }
    }
#pragma unroll
    for (int db = 0; db < 4; db++)
#pragma unroll
        for (int r = 0; r < 4; r++) {
            int rowi = q0 + lq * 4 + r;
            float v = O[db][r] * (1.0f / lrow[r]);
            size_t off = (size_t)rowi * 1024 + h * 64 + db * 16 + lr;
            if (SPLIT) { bf16 hh, ll; split_bf(v, hh, ll); oh[off] = hh; ol[off] = ll; }
            else oh[off] = __float2bfloat16(v);
        }
}

// ---------------- router: fused f32 rmsnorm + logits + top2 softmax -> wfull[T,8] ----------------
__global__ __launch_bounds__(256) void gate_kernel(
    const float* __restrict__ hb, const float* __restrict__ lnw,
    const float* __restrict__ gw, float* __restrict__ wfull)
{
    int t = blockIdx.x * 4 + (threadIdx.x >> 6);
    int lane = threadIdx.x & 63;
    float ss = 0.f, acc[8];
#pragma unroll
    for (int e = 0; e < 8; e++) acc[e] = 0.f;
    for (int i = lane; i < H; i += 64) {
        float hv = hb[(size_t)t * H + i];
        ss += hv * hv;
        float xv = hv * lnw[i];
        const float* g = gw + (size_t)i * 8;
#pragma unroll
        for (int e = 0; e < 8; e++) acc[e] += xv * g[e];
    }
#pragma unroll
    for (int off = 32; off > 0; off >>= 1) {
        ss += __shfl_xor(ss, off);
#pragma unroll
        for (int e = 0; e < 8; e++) acc[e] += __shfl_xor(acc[e], off);
    }
    if (lane == 0) {
        float rms = rsqrtf(ss * (1.0f / H) + 1e-6f);
        float best = -3.4e38f, second = -3.4e38f;
        int bi = 0, si = 0;
#pragma unroll
        for (int e = 0; e < 8; e++) {
            float v = acc[e] * rms;
            if (v > best) { second = best; si = bi; best = v; bi = e; }
            else if (v > second) { second = v; si = e; }
        }
        float ew = __expf(second - best);
        float wb = 1.f / (1.f + ew);
        float ws2 = ew / (1.f + ew);
#pragma unroll
        for (int e = 0; e < 8; e++)
            wfull[(size_t)t * 8 + e] = (e == bi) ? wb : ((e == si) ? ws2 : 0.f);
    }
}

// ---------------- G = silu(a1)*a3*w_full ----------------
template<int SPLIT>
__global__ __launch_bounds__(256) void moe_act_kernel(
    const void* __restrict__ a13, const float* __restrict__ wfull,
    bf16* __restrict__ gh, bf16* __restrict__ gl)
{
    size_t idx = ((size_t)blockIdx.x * 256 + threadIdx.x) * 4;
    int t = (int)(idx >> 13);
    int c = (int)(idx & 8191);
    int e = c >> 10;
    float wv = wfull[(size_t)t * 8 + e];
#pragma unroll
    for (int j = 0; j < 4; j++) {
        float a, b;
        if (SPLIT) {
            const float* p = (const float*)a13 + (size_t)t * 16384;
            a = p[c + j]; b = p[8192 + c + j];
        } else {
            const bf16* p = (const bf16*)a13 + (size_t)t * 16384;
            a = __bfloat162float(p[c + j]); b = __bfloat162float(p[8192 + c + j]);
        }
        float sig = 1.f / (1.f + __expf(-a));
        float g = a * sig * b * wv;
        size_t off = (size_t)t * 8192 + c + j;
        if (SPLIT) { bf16 hh, ll; split_bf(g, hh, ll); gh[off] = hh; gl[off] = ll; }
        else gh[off] = __float2bfloat16(g);
    }
}

extern "C" void kernel_launch(void* const* d_in, const int* in_sizes, int n_in,
                              void* d_out, int out_size, void* d_ws, size_t ws_size,
                              hipStream_t stream)
{
    const int*   ids   = (const int*)d_in[0];
    const int*   pos   = (const int*)d_in[1];
    const float* emb   = (const float*)d_in[2];
    const float* ln1   = (const float*)d_in[3];
    const float* Wq    = (const float*)d_in[4];
    const float* Wk    = (const float*)d_in[5];
    const float* Wv    = (const float*)d_in[6];
    const float* Wo    = (const float*)d_in[7];
    const float* ln2   = (const float*)d_in[8];
    const float* gw    = (const float*)d_in[9];
    const float* w1    = (const float*)d_in[10];
    const float* w3    = (const float*)d_in[11];
    const float* w2    = (const float*)d_in[12];
    const float* normw = (const float*)d_in[13];

    char* p = (char*)d_ws;
    auto alloc = [&](size_t bytes) -> char* {
        char* r = p; p += (bytes + 255) & ~(size_t)255; return r;
    };
    const size_t QKV_E = (size_t)2048 * 1024, WO_E = (size_t)1024 * 1024;
    const size_t W13_E = (size_t)16384 * 1024, W2_E = (size_t)1024 * 8192;
    bf16 *qkvtH[L], *wotH[L], *w13tH[L], *w2tH[L];
    for (int l = 0; l < L; l++) {
        qkvtH[l] = (bf16*)alloc(QKV_E * 2);
        wotH[l]  = (bf16*)alloc(WO_E * 2);
        w13tH[l] = (bf16*)alloc(W13_E * 2);
        w2tH[l]  = (bf16*)alloc(W2_E * 2);
    }
    bf16* qkvtL = (bf16*)alloc(QKV_E * 2);
    bf16* wotL  = (bf16*)alloc(WO_E * 2);
    bf16* w13tL = (bf16*)alloc(W13_E * 2);
    bf16* w2tL  = (bf16*)alloc(W2_E * 2);

    float* hbuf = (float*)alloc((size_t)S * H * 4);
    bf16* xh    = (bf16*)alloc((size_t)S * H * 2);
    bf16* xl    = (bf16*)alloc((size_t)S * H * 2);
    bf16* qkvh  = (bf16*)alloc((size_t)S * 2048 * 2);
    bf16* qkvl  = (bf16*)alloc((size_t)S * 2048 * 2);
    bf16* qrb   = (bf16*)alloc((size_t)NH * S * 64 * 2);
    bf16* krb   = (bf16*)alloc((size_t)NKV * S * 64 * 2);
    bf16* vthb  = (bf16*)alloc((size_t)NKV * 64 * S * 2);
    bf16* vtlb  = (bf16*)alloc((size_t)NKV * 64 * S * 2);
    bf16* ohb   = (bf16*)alloc((size_t)S * 1024 * 2);
    bf16* olb   = (bf16*)alloc((size_t)S * 1024 * 2);
    float* a13f = (float*)alloc((size_t)CH * 16384 * 4);   // also reused as bf16 for L2
    bf16* ghb   = (bf16*)alloc((size_t)CH * 8192 * 2);
    bf16* glb   = (bf16*)alloc((size_t)CH * 8192 * 2);
    float* wfull = (float*)alloc((size_t)S * 8 * 4);

    // ---- weight transpose+convert: layer 0 split, layer 1 plain ----
    for (int l = 0; l < L; l++) {
        const float* wq_l = Wq + (size_t)l * 1024 * 1024;
        const float* wk_l = Wk + (size_t)l * 1024 * 512;
        const float* wv_l = Wv + (size_t)l * 1024 * 512;
        const float* wo_l = Wo + (size_t)l * 1024 * 1024;
        const float* w1_l = w1 + (size_t)l * 8 * 1024 * 1024;
        const float* w3_l = w3 + (size_t)l * 8 * 1024 * 1024;
        const float* w2_l = w2 + (size_t)l * 8 * 1024 * 1024;
        if (l == 0) {
            transpose_cvt<1><<<dim3(32, 32, 1), 256, 0, stream>>>(wq_l, qkvtH[0], qkvtL, 1024, 0, 0, 1024);
            transpose_cvt<1><<<dim3(16, 32, 1), 256, 0, stream>>>(wk_l, qkvtH[0] + WO_E, qkvtL + WO_E, 512, 0, 0, 1024);
            transpose_cvt<1><<<dim3(16, 32, 1), 256, 0, stream>>>(wv_l, qkvtH[0] + WO_E + WO_E / 2, qkvtL + WO_E + WO_E / 2, 512, 0, 0, 1024);
            transpose_cvt<1><<<dim3(32, 32, 1), 256, 0, stream>>>(wo_l, wotH[0], wotL, 1024, 0, 0, 1024);
            transpose_cvt<1><<<dim3(32, 32, 8), 256, 0, stream>>>(w1_l, w13tH[0], w13tL, 1024, 1024 * 1024, 1024 * 1024, 1024);
            transpose_cvt<1><<<dim3(32, 32, 8), 256, 0, stream>>>(w3_l, w13tH[0] + (size_t)8192 * 1024, w13tL + (size_t)8192 * 1024, 1024, 1024 * 1024, 1024 * 1024, 1024);
            transpose_cvt<1><<<dim3(32, 32, 8), 256, 0, stream>>>(w2_l, w2tH[0], w2tL, 1024, 1024 * 1024, 1024, 8192);
        } else {
            transpose_cvt<0><<<dim3(32, 32, 1), 256, 0, stream>>>(wq_l, qkvtH[1], nullptr, 1024, 0, 0, 1024);
            transpose_cvt<0><<<dim3(16, 32, 1), 256, 0, stream>>>(wk_l, qkvtH[1] + WO_E, nullptr, 512, 0, 0, 1024);
            transpose_cvt<0><<<dim3(16, 32, 1), 256, 0, stream>>>(wv_l, qkvtH[1] + WO_E + WO_E / 2, nullptr, 512, 0, 0, 1024);
            transpose_cvt<0><<<dim3(32, 32, 1), 256, 0, stream>>>(wo_l, wotH[1], nullptr, 1024, 0, 0, 1024);
            transpose_cvt<0><<<dim3(32, 32, 8), 256, 0, stream>>>(w1_l, w13tH[1], nullptr, 1024, 1024 * 1024, 1024 * 1024, 1024);
            transpose_cvt<0><<<dim3(32, 32, 8), 256, 0, stream>>>(w3_l, w13tH[1] + (size_t)8192 * 1024, nullptr, 1024, 1024 * 1024, 1024 * 1024, 1024);
            transpose_cvt<0><<<dim3(32, 32, 8), 256, 0, stream>>>(w2_l, w2tH[1], nullptr, 1024, 1024 * 1024, 1024, 8192);
        }
    }

    embed_kernel<<<S, 256, 0, stream>>>(ids, emb, hbuf);

    for (int l = 0; l < L; l++) {
        if (l == 0) {
            // ======== layer 0: split-bf16 precision (routing-exact residual stream) ========
            rmsnorm_kernel<2><<<S, 256, 0, stream>>>(hbuf, ln1, xh, xl, nullptr);
            gemm_bt<128, 128, 1, 1><<<dim3(16, 16), 256, 0, stream>>>(
                xh, xl, qkvtH[0], qkvtL, qkvh, qkvl, 1024, 1024, 2048, 1.0f);
            rope_kernel<1><<<S, 256, 0, stream>>>(qkvh, qkvl, pos, qrb, krb, vthb, vtlb);
            attn_kernel<1><<<dim3(32, 16), 256, 0, stream>>>(qrb, krb, vthb, vtlb, ohb, olb);
            gemm_bt<64, 128, 1, 3><<<dim3(8, 32), 256, 0, stream>>>(
                ohb, olb, wotH[0], wotL, hbuf, nullptr, 1024, 1024, 1024, RES_MULT);

            gate_kernel<<<512, 256, 0, stream>>>(hbuf, ln2, gw, wfull);
            rmsnorm_kernel<2><<<S, 256, 0, stream>>>(hbuf, ln2, xh, xl, nullptr);
            for (int c = 0; c < S / CH; c++) {
                gemm_bt<128, 128, 1, 2><<<dim3(128, CH / 128), 256, 0, stream>>>(
                    xh + (size_t)c * CH * 1024, xl + (size_t)c * CH * 1024,
                    w13tH[0], w13tL, a13f, nullptr, 1024, 1024, 16384, 1.0f);
                moe_act_kernel<1><<<CH * 8192 / 1024, 256, 0, stream>>>(
                    a13f, wfull + (size_t)c * CH * 8, ghb, glb);
                gemm_bt<64, 128, 1, 3><<<dim3(8, CH / 64), 256, 0, stream>>>(
                    ghb, glb, w2tH[0], w2tL, hbuf + (size_t)c * CH * 1024, nullptr,
                    8192, 8192, 1024, RES_MULT);
            }
        } else {
            // ======== layer 1: plain bf16 (feeds only the 2%-tolerance output) ========
            rmsnorm_kernel<1><<<S, 256, 0, stream>>>(hbuf, ln1 + H, xh, nullptr, nullptr);
            gemm_bt<128, 128, 0, 0><<<dim3(16, 16), 256, 0, stream>>>(
                xh, nullptr, qkvtH[1], nullptr, qkvh, nullptr, 1024, 1024, 2048, 1.0f);
            rope_kernel<0><<<S, 256, 0, stream>>>(qkvh, nullptr, pos, qrb, krb, vthb, nullptr);
            attn_kernel<0><<<dim3(32, 16), 256, 0, stream>>>(qrb, krb, vthb, nullptr, ohb, nullptr);
            gemm_bt<64, 128, 0, 3><<<dim3(8, 32), 256, 0, stream>>>(
                ohb, nullptr, wotH[1], nullptr, hbuf, nullptr, 1024, 1024, 1024, RES_MULT);

            gate_kernel<<<512, 256, 0, stream>>>(hbuf, ln2 + H, gw + (size_t)H * 8, wfull);
            rmsnorm_kernel<1><<<S, 256, 0, stream>>>(hbuf, ln2 + H, xh, nullptr, nullptr);
            for (int c = 0; c < S / CH; c++) {
                gemm_bt<128, 128, 0, 0><<<dim3(128, CH / 128), 256, 0, stream>>>(
                    xh + (size_t)c * CH * 1024, nullptr, w13tH[1], nullptr,
                    (bf16*)a13f, nullptr, 1024, 1024, 16384, 1.0f);
                moe_act_kernel<0><<<CH * 8192 / 1024, 256, 0, stream>>>(
                    (bf16*)a13f, wfull + (size_t)c * CH * 8, ghb, nullptr);
                gemm_bt<64, 128, 0, 3><<<dim3(8, CH / 64), 256, 0, stream>>>(
                    ghb, nullptr, w2tH[1], nullptr, hbuf + (size_t)c * CH * 1024, nullptr,
                    8192, 8192, 1024, RES_MULT);
            }
        }
    }

    rmsnorm_kernel<0><<<S, 256, 0, stream>>>(hbuf, normw, nullptr, nullptr, (float*)d_out);
}

// Round 3
// 1162.837 us; speedup vs baseline: 2.3597x; 2.3597x over previous
//
#include <hip/hip_runtime.h>
#include <hip/hip_bf16.h>
#include <math.h>

typedef __hip_bfloat16 bf16;
typedef short bf16x8 __attribute__((ext_vector_type(8)));
typedef float f32x4 __attribute__((ext_vector_type(4)));

static constexpr int S   = 2048;
static constexpr int H   = 1024;
static constexpr int NH  = 16;
static constexpr int NKV = 8;
static constexpr int L   = 2;
static constexpr int NASSIGN = S * 2;      // top-2: exactly 4096 assignment rows
static constexpr int MAXBLK  = 72;         // ceil(4096/64)+8 pad

#define ATTN_MULT 0.015625f
#define RES_MULT  0.22f

__device__ inline void split_bf(float v, bf16& h, bf16& l) {
    h = __float2bfloat16(v);
    l = __float2bfloat16(v - __bfloat162float(h));
}

// ---------------- tiled transpose + f32 -> bf16 (optionally split) ----------------
template<int SPLIT>
__global__ __launch_bounds__(256) void transpose_cvt(
    const float* __restrict__ in, bf16* __restrict__ oh, bf16* __restrict__ ol,
    int N, long in_bstride, long out_bstride, int out_ld)
{
    __shared__ float tile[32][33];
    int b = blockIdx.z;
    const float* inp = in + (size_t)b * in_bstride;
    int k0 = blockIdx.y * 32, n0 = blockIdx.x * 32;
    int tx = threadIdx.x & 31, ty = threadIdx.x >> 5;
#pragma unroll
    for (int i = 0; i < 4; i++)
        tile[ty + i * 8][tx] = inp[(size_t)(k0 + ty + i * 8) * N + n0 + tx];
    __syncthreads();
#pragma unroll
    for (int i = 0; i < 4; i++) {
        int n = ty + i * 8;
        size_t off = (size_t)b * out_bstride + (size_t)(n0 + n) * out_ld + k0 + tx;
        float v = tile[tx][n];
        if (SPLIT) { bf16 h, l; split_bf(v, h, l); oh[off] = h; ol[off] = l; }
        else oh[off] = __float2bfloat16(v);
    }
}

// ---------------- embedding gather ----------------
__global__ __launch_bounds__(256) void embed_kernel(
    const int* __restrict__ ids, const float* __restrict__ emb, float* __restrict__ h)
{
    int t = blockIdx.x;
    int id = ids[t];
    const float4* src = (const float4*)(emb + (size_t)id * H);
    float4* dst = (float4*)(h + (size_t)t * H);
    float4 v = src[threadIdx.x];
    v.x *= 12.0f; v.y *= 12.0f; v.z *= 12.0f; v.w *= 12.0f;
    dst[threadIdx.x] = v;
}

// ---------------- RMSNorm: MODE 0 = f32 out, 1 = bf16, 2 = split bf16 ----------------
template<int MODE>
__global__ __launch_bounds__(256) void rmsnorm_kernel(
    const float* __restrict__ hbuf, const float* __restrict__ w,
    bf16* __restrict__ oh, bf16* __restrict__ ol, float* __restrict__ of)
{
    int t = blockIdx.x;
    const float4* row = (const float4*)(hbuf + (size_t)t * H);
    float4 v = row[threadIdx.x];
    float ss = v.x * v.x + v.y * v.y + v.z * v.z + v.w * v.w;
#pragma unroll
    for (int off = 32; off > 0; off >>= 1) ss += __shfl_xor(ss, off);
    __shared__ float wsum[4];
    if ((threadIdx.x & 63) == 0) wsum[threadIdx.x >> 6] = ss;
    __syncthreads();
    float tot = wsum[0] + wsum[1] + wsum[2] + wsum[3];
    float rms = rsqrtf(tot * (1.0f / H) + 1e-6f);
    const float4* wp = (const float4*)w;
    float4 wv = wp[threadIdx.x];
    float o[4] = { v.x * rms * wv.x, v.y * rms * wv.y, v.z * rms * wv.z, v.w * rms * wv.w };
    size_t base = (size_t)t * H + threadIdx.x * 4;
    if (MODE == 0) {
#pragma unroll
        for (int j = 0; j < 4; j++) of[base + j] = o[j];
    } else if (MODE == 1) {
#pragma unroll
        for (int j = 0; j < 4; j++) oh[base + j] = __float2bfloat16(o[j]);
    } else {
#pragma unroll
        for (int j = 0; j < 4; j++) { bf16 h, l; split_bf(o[j], h, l); oh[base + j] = h; ol[base + j] = l; }
    }
}

// ---------------- GEMM: C[M,N] = A[M,K] @ Bt[N,K]^T, optional split-K ----------------
// CMODE 0: bf16 store; 1: split bf16 store; 2: f32 store; 3: f32 atomicAdd (residual)
template<int BM, int BN, int SPLIT, int CMODE, int SPLITK>
__global__ __launch_bounds__(256) void gemm_bt(
    const bf16* __restrict__ Ah, const bf16* __restrict__ Al,
    const bf16* __restrict__ Bh, const bf16* __restrict__ Bl,
    void* __restrict__ Ch, bf16* __restrict__ Cl,
    int Kd, int lda, int ldc, float scale)
{
    constexpr int BK = 32, PADE = 40;
    __shared__ __align__(16) bf16 Ash[BM][PADE];
    __shared__ __align__(16) bf16 Bsh[BN][PADE];
    __shared__ __align__(16) bf16 Asl[SPLIT ? BM : 1][PADE];
    __shared__ __align__(16) bf16 Bsl[SPLIT ? BN : 1][PADE];
    int m0 = blockIdx.y * BM, n0 = blockIdx.x * BN;
    int kseg = Kd / SPLITK;
    int kbeg = blockIdx.z * kseg, kend = kbeg + kseg;
    int tid = threadIdx.x;
    int wave = tid >> 6, lane = tid & 63;
    int wm = wave >> 1, wn = wave & 1;
    constexpr int WM = BM / 2, WN = BN / 2;
    constexpr int MT = WM / 16, NT = WN / 16;
    int lr = lane & 15, lq = lane >> 4;
    f32x4 acc[MT][NT];
    f32x4 zero = {0.f, 0.f, 0.f, 0.f};
#pragma unroll
    for (int i = 0; i < MT; i++)
#pragma unroll
        for (int j = 0; j < NT; j++) acc[i][j] = zero;

    for (int k0 = kbeg; k0 < kend; k0 += BK) {
#pragma unroll
        for (int it = 0; it < BM / 64; it++) {
            int idx = tid + it * 256;
            int r = idx >> 2, c = (idx & 3) * 8;
            *(bf16x8*)&Ash[r][c] = *(const bf16x8*)(Ah + (size_t)(m0 + r) * lda + k0 + c);
            if (SPLIT)
                *(bf16x8*)&Asl[r][c] = *(const bf16x8*)(Al + (size_t)(m0 + r) * lda + k0 + c);
        }
#pragma unroll
        for (int it = 0; it < BN / 64; it++) {
            int idx = tid + it * 256;
            int r = idx >> 2, c = (idx & 3) * 8;
            *(bf16x8*)&Bsh[r][c] = *(const bf16x8*)(Bh + (size_t)(n0 + r) * Kd + k0 + c);
            if (SPLIT)
                *(bf16x8*)&Bsl[r][c] = *(const bf16x8*)(Bl + (size_t)(n0 + r) * Kd + k0 + c);
        }
        __syncthreads();
        bf16x8 ah[MT], bh[NT];
#pragma unroll
        for (int mt = 0; mt < MT; mt++)
            ah[mt] = *(const bf16x8*)&Ash[wm * WM + mt * 16 + lr][lq * 8];
#pragma unroll
        for (int nt = 0; nt < NT; nt++)
            bh[nt] = *(const bf16x8*)&Bsh[wn * WN + nt * 16 + lr][lq * 8];
#pragma unroll
        for (int mt = 0; mt < MT; mt++)
#pragma unroll
            for (int nt = 0; nt < NT; nt++)
                acc[mt][nt] = __builtin_amdgcn_mfma_f32_16x16x32_bf16(ah[mt], bh[nt], acc[mt][nt], 0, 0, 0);
        if (SPLIT) {
            bf16x8 al[MT], bl[NT];
#pragma unroll
            for (int mt = 0; mt < MT; mt++)
                al[mt] = *(const bf16x8*)&Asl[wm * WM + mt * 16 + lr][lq * 8];
#pragma unroll
            for (int nt = 0; nt < NT; nt++)
                bl[nt] = *(const bf16x8*)&Bsl[wn * WN + nt * 16 + lr][lq * 8];
#pragma unroll
            for (int mt = 0; mt < MT; mt++)
#pragma unroll
                for (int nt = 0; nt < NT; nt++) {
                    acc[mt][nt] = __builtin_amdgcn_mfma_f32_16x16x32_bf16(ah[mt], bl[nt], acc[mt][nt], 0, 0, 0);
                    acc[mt][nt] = __builtin_amdgcn_mfma_f32_16x16x32_bf16(al[mt], bh[nt], acc[mt][nt], 0, 0, 0);
                }
        }
        __syncthreads();
    }
#pragma unroll
    for (int mt = 0; mt < MT; mt++)
#pragma unroll
        for (int nt = 0; nt < NT; nt++)
#pragma unroll
            for (int r = 0; r < 4; r++) {
                int m = m0 + wm * WM + mt * 16 + lq * 4 + r;
                int n = n0 + wn * WN + nt * 16 + lr;
                float v = acc[mt][nt][r] * scale;
                size_t off = (size_t)m * ldc + n;
                if (CMODE == 0)      ((bf16*)Ch)[off] = __float2bfloat16(v);
                else if (CMODE == 1) { bf16 h, l; split_bf(v, h, l); ((bf16*)Ch)[off] = h; Cl[off] = l; }
                else if (CMODE == 2) ((float*)Ch)[off] = v;
                else                 atomicAdd(&((float*)Ch)[off], v);
            }
}

// ---------------- RoPE + layout ----------------
template<int SPLIT>
__global__ __launch_bounds__(256) void rope_kernel(
    const bf16* __restrict__ qkvh, const bf16* __restrict__ qkvl, const int* __restrict__ pos,
    bf16* __restrict__ qr, bf16* __restrict__ kr, bf16* __restrict__ vth, bf16* __restrict__ vtl)
{
    int s = blockIdx.x;
    float p = (float)pos[s];
    int tid = threadIdx.x;
    const bf16* rowh = qkvh + (size_t)s * 2048;
    const bf16* rowl = SPLIT ? qkvl + (size_t)s * 2048 : nullptr;
    auto val = [&](int off) -> float {
        float v = __bfloat162float(rowh[off]);
        if (SPLIT) v += __bfloat162float(rowl[off]);
        return v;
    };
    for (int idx = tid; idx < 512; idx += 256) {
        int hq = idx >> 5, d = idx & 31;
        float inv = __expf(-(float)d * (9.210340371976184f / 32.0f));
        float sn, cs;
        sincosf(p * inv, &sn, &cs);
        float x1 = val(hq * 64 + d), x2 = val(hq * 64 + d + 32);
        qr[((size_t)hq * S + s) * 64 + d]      = __float2bfloat16(x1 * cs - x2 * sn);
        qr[((size_t)hq * S + s) * 64 + d + 32] = __float2bfloat16(x2 * cs + x1 * sn);
    }
    if (tid < 256) {
        int hk = tid >> 5, d = tid & 31;
        float inv = __expf(-(float)d * (9.210340371976184f / 32.0f));
        float sn, cs;
        sincosf(p * inv, &sn, &cs);
        float x1 = val(1024 + hk * 64 + d), x2 = val(1024 + hk * 64 + d + 32);
        kr[((size_t)hk * S + s) * 64 + d]      = __float2bfloat16(x1 * cs - x2 * sn);
        kr[((size_t)hk * S + s) * 64 + d + 32] = __float2bfloat16(x2 * cs + x1 * sn);
    }
    for (int idx = tid; idx < 512; idx += 256) {
        int hk = idx >> 6, d = idx & 63;
        vth[((size_t)hk * 64 + d) * S + s] = rowh[1536 + idx];
        if (SPLIT) vtl[((size_t)hk * 64 + d) * S + s] = rowl[1536 + idx];
    }
}

// ---------------- Flash attention ----------------
template<int SPLIT>
__global__ __launch_bounds__(256) void attn_kernel(
    const bf16* __restrict__ qr, const bf16* __restrict__ kr,
    const bf16* __restrict__ vth, const bf16* __restrict__ vtl,
    bf16* __restrict__ oh, bf16* __restrict__ ol)
{
    __shared__ __align__(16) bf16 Psh[4][16][40];
    __shared__ __align__(16) bf16 Psl[SPLIT ? 4 : 1][16][40];
    int wave = threadIdx.x >> 6, lane = threadIdx.x & 63;
    int lr = lane & 15, lq = lane >> 4;
    int h = blockIdx.y, hk = h >> 1;
    int q0 = blockIdx.x * 64 + wave * 16;

    const bf16* qbase = qr + ((size_t)h * S + q0 + lr) * 64 + lq * 8;
    bf16x8 qf0 = *(const bf16x8*)qbase;
    bf16x8 qf1 = *(const bf16x8*)(qbase + 32);

    f32x4 O[4];
    f32x4 zero = {0.f, 0.f, 0.f, 0.f};
#pragma unroll
    for (int db = 0; db < 4; db++) O[db] = zero;
    float mrow[4] = {-1e30f, -1e30f, -1e30f, -1e30f};
    float lrow[4] = {0.f, 0.f, 0.f, 0.f};
    int qmax = q0 + 15;

    for (int k0 = 0; k0 <= qmax; k0 += 32) {
        float sv[2][4];
#pragma unroll
        for (int nb = 0; nb < 2; nb++) {
            const bf16* kbase = kr + ((size_t)hk * S + k0 + nb * 16 + lr) * 64 + lq * 8;
            f32x4 sacc = zero;
            sacc = __builtin_amdgcn_mfma_f32_16x16x32_bf16(qf0, *(const bf16x8*)kbase, sacc, 0, 0, 0);
            sacc = __builtin_amdgcn_mfma_f32_16x16x32_bf16(qf1, *(const bf16x8*)(kbase + 32), sacc, 0, 0, 0);
            int col = k0 + nb * 16 + lr;
#pragma unroll
            for (int r = 0; r < 4; r++) {
                int rowi = q0 + lq * 4 + r;
                sv[nb][r] = (col <= rowi) ? sacc[r] * ATTN_MULT : -1e9f;
            }
        }
        float rm[4];
#pragma unroll
        for (int r = 0; r < 4; r++) rm[r] = fmaxf(sv[0][r], sv[1][r]);
#pragma unroll
        for (int off = 1; off < 16; off <<= 1)
#pragma unroll
            for (int r = 0; r < 4; r++) rm[r] = fmaxf(rm[r], __shfl_xor(rm[r], off));
        float alpha[4], rs[4];
#pragma unroll
        for (int r = 0; r < 4; r++) {
            float mn = fmaxf(mrow[r], rm[r]);
            alpha[r] = __expf(mrow[r] - mn);
            mrow[r] = mn;
            sv[0][r] = __expf(sv[0][r] - mn);
            sv[1][r] = __expf(sv[1][r] - mn);
            rs[r] = sv[0][r] + sv[1][r];
        }
#pragma unroll
        for (int off = 1; off < 16; off <<= 1)
#pragma unroll
            for (int r = 0; r < 4; r++) rs[r] += __shfl_xor(rs[r], off);
#pragma unroll
        for (int r = 0; r < 4; r++) lrow[r] = lrow[r] * alpha[r] + rs[r];
#pragma unroll
        for (int db = 0; db < 4; db++)
#pragma unroll
            for (int r = 0; r < 4; r++) O[db][r] *= alpha[r];
#pragma unroll
        for (int nb = 0; nb < 2; nb++)
#pragma unroll
            for (int r = 0; r < 4; r++) {
                if (SPLIT) {
                    bf16 hh, ll; split_bf(sv[nb][r], hh, ll);
                    Psh[wave][lq * 4 + r][nb * 16 + lr] = hh;
                    Psl[wave][lq * 4 + r][nb * 16 + lr] = ll;
                } else {
                    Psh[wave][lq * 4 + r][nb * 16 + lr] = __float2bfloat16(sv[nb][r]);
                }
            }
        __asm volatile("s_waitcnt lgkmcnt(0)" ::: "memory");
        bf16x8 pfh = *(const bf16x8*)&Psh[wave][lr][lq * 8];
        bf16x8 pfl;
        if (SPLIT) pfl = *(const bf16x8*)&Psl[wave][lr][lq * 8];
#pragma unroll
        for (int db = 0; db < 4; db++) {
            size_t vtoff = ((size_t)hk * 64 + db * 16 + lr) * S + k0 + lq * 8;
            bf16x8 vfh = *(const bf16x8*)(vth + vtoff);
            O[db] = __builtin_amdgcn_mfma_f32_16x16x32_bf16(pfh, vfh, O[db], 0, 0, 0);
            if (SPLIT) {
                bf16x8 vfl = *(const bf16x8*)(vtl + vtoff);
                O[db] = __builtin_amdgcn_mfma_f32_16x16x32_bf16(pfh, vfl, O[db], 0, 0, 0);
                O[db] = __builtin_amdgcn_mfma_f32_16x16x32_bf16(pfl, vfh, O[db], 0, 0, 0);
            }
        }
    }
#pragma unroll
    for (int db = 0; db < 4; db++)
#pragma unroll
        for (int r = 0; r < 4; r++) {
            int rowi = q0 + lq * 4 + r;
            float v = O[db][r] * (1.0f / lrow[r]);
            size_t off = (size_t)rowi * 1024 + h * 64 + db * 16 + lr;
            if (SPLIT) { bf16 hh, ll; split_bf(v, hh, ll); oh[off] = hh; ol[off] = ll; }
            else oh[off] = __float2bfloat16(v);
        }
}

// ---------------- router: fused f32 rmsnorm + logits -> top2 idx/weights ----------------
__global__ __launch_bounds__(256) void gate_kernel(
    const float* __restrict__ hb, const float* __restrict__ lnw,
    const float* __restrict__ gw, int* __restrict__ top_idx, float* __restrict__ top_w)
{
    int t = blockIdx.x * 4 + (threadIdx.x >> 6);
    int lane = threadIdx.x & 63;
    float ss = 0.f, acc[8];
#pragma unroll
    for (int e = 0; e < 8; e++) acc[e] = 0.f;
    for (int i = lane; i < H; i += 64) {
        float hv = hb[(size_t)t * H + i];
        ss += hv * hv;
        float xv = hv * lnw[i];
        const float* g = gw + (size_t)i * 8;
#pragma unroll
        for (int e = 0; e < 8; e++) acc[e] += xv * g[e];
    }
#pragma unroll
    for (int off = 32; off > 0; off >>= 1) {
        ss += __shfl_xor(ss, off);
#pragma unroll
        for (int e = 0; e < 8; e++) acc[e] += __shfl_xor(acc[e], off);
    }
    if (lane == 0) {
        float rms = rsqrtf(ss * (1.0f / H) + 1e-6f);
        float best = -3.4e38f, second = -3.4e38f;
        int bi = 0, si = 0;
#pragma unroll
        for (int e = 0; e < 8; e++) {
            float v = acc[e] * rms;
            if (v > best) { second = best; si = bi; best = v; bi = e; }
            else if (v > second) { second = v; si = e; }
        }
        float ew = __expf(second - best);
        top_idx[t * 2] = bi;  top_idx[t * 2 + 1] = si;
        top_w[t * 2] = 1.f / (1.f + ew);
        top_w[t * 2 + 1] = ew / (1.f + ew);
    }
}

// ---------------- build per-expert assignment lists + block descriptors ----------------
__global__ __launch_bounds__(256) void route_build(
    const int* __restrict__ top_idx, const float* __restrict__ top_w,
    int* __restrict__ row_token, float* __restrict__ row_w, int4* __restrict__ desc)
{
    __shared__ int cnt[8], pos[8];
    int tid = threadIdx.x;
    if (tid < 8) cnt[tid] = 0;
    __syncthreads();
    for (int i = tid; i < NASSIGN; i += 256) atomicAdd(&cnt[top_idx[i]], 1);
    __syncthreads();
    if (tid == 0) {
        int o = 0, nb = 0;
        for (int e = 0; e < 8; e++) {
            pos[e] = o;
            for (int m0 = 0; m0 < cnt[e]; m0 += 64) {
                int vr = cnt[e] - m0; if (vr > 64) vr = 64;
                desc[nb] = make_int4(e, o + m0, vr, 0);
                nb++;
            }
            o += cnt[e];
        }
        for (int b = nb; b < MAXBLK; b++) desc[b] = make_int4(0, 0, 0, 0);
        desc[MAXBLK] = make_int4(nb, 0, 0, 0);
    }
    __syncthreads();
    for (int i = tid; i < NASSIGN; i += 256) {
        int e = top_idx[i];
        int p = atomicAdd(&pos[e], 1);
        row_token[p] = i >> 1;
        row_w[p] = top_w[i];
    }
}

// ---------------- per-expert GEMM (BM=64 rows of the assignment list) ----------------
// INDIRECT: A row gathered via row_token.  CMODE 0: bf16 C at compact rows;
// 2: f32 C at compact rows; 4: scatter atomicAdd into hout[token*1024+n].
template<int BN, int SPLIT, int INDIRECT, int CMODE>
__global__ __launch_bounds__(256) void moe_gemm(
    const bf16* __restrict__ Ah, const bf16* __restrict__ Al, int lda,
    const bf16* __restrict__ Bh, const bf16* __restrict__ Bl, long ebstride, int Kd,
    const int* __restrict__ row_token, const int4* __restrict__ desc_arr,
    void* __restrict__ C0, bf16* __restrict__ C1, int ldc, float scale,
    float* __restrict__ hout)
{
    int nblk = desc_arr[MAXBLK].x;
    if ((int)blockIdx.y >= nblk) return;
    int4 dsc = desc_arr[blockIdx.y];
    int e = dsc.x, grow0 = dsc.y, valid = dsc.z;
    constexpr int BM = 64, BK = 32, PADE = 40;
    __shared__ __align__(16) bf16 Ash[BM][PADE];
    __shared__ __align__(16) bf16 Bsh[BN][PADE];
    __shared__ __align__(16) bf16 Asl[SPLIT ? BM : 1][PADE];
    __shared__ __align__(16) bf16 Bsl[SPLIT ? BN : 1][PADE];
    const bf16* Bhe = Bh + (size_t)e * ebstride;
    const bf16* Ble = SPLIT ? Bl + (size_t)e * ebstride : nullptr;
    int tid = threadIdx.x;
    int arow = tid >> 2, ac = (tid & 3) * 8;
    int gr = grow0 + (arow < valid ? arow : valid - 1);
    int tok = INDIRECT ? row_token[gr] : gr;
    const bf16* aptr  = Ah + (size_t)tok * lda + ac;
    const bf16* alptr = SPLIT ? Al + (size_t)tok * lda + ac : nullptr;
    int n0 = blockIdx.x * BN;
    int wave = tid >> 6, lane = tid & 63;
    int wm = wave >> 1, wn = wave & 1;
    constexpr int WM = 32, WN = BN / 2;
    constexpr int MT = 2, NT = WN / 16;
    int lr = lane & 15, lq = lane >> 4;
    f32x4 acc[MT][NT];
    f32x4 zero = {0.f, 0.f, 0.f, 0.f};
#pragma unroll
    for (int i = 0; i < MT; i++)
#pragma unroll
        for (int j = 0; j < NT; j++) acc[i][j] = zero;

    for (int k0 = 0; k0 < Kd; k0 += BK) {
        *(bf16x8*)&Ash[arow][ac] = *(const bf16x8*)(aptr + k0);
        if (SPLIT) *(bf16x8*)&Asl[arow][ac] = *(const bf16x8*)(alptr + k0);
#pragma unroll
        for (int it = 0; it < BN / 64; it++) {
            int idx = tid + it * 256;
            int r = idx >> 2, c = (idx & 3) * 8;
            *(bf16x8*)&Bsh[r][c] = *(const bf16x8*)(Bhe + (size_t)(n0 + r) * Kd + k0 + c);
            if (SPLIT)
                *(bf16x8*)&Bsl[r][c] = *(const bf16x8*)(Ble + (size_t)(n0 + r) * Kd + k0 + c);
        }
        __syncthreads();
        bf16x8 ah[MT], bh[NT];
#pragma unroll
        for (int mt = 0; mt < MT; mt++)
            ah[mt] = *(const bf16x8*)&Ash[wm * WM + mt * 16 + lr][lq * 8];
#pragma unroll
        for (int nt = 0; nt < NT; nt++)
            bh[nt] = *(const bf16x8*)&Bsh[wn * WN + nt * 16 + lr][lq * 8];
#pragma unroll
        for (int mt = 0; mt < MT; mt++)
#pragma unroll
            for (int nt = 0; nt < NT; nt++)
                acc[mt][nt] = __builtin_amdgcn_mfma_f32_16x16x32_bf16(ah[mt], bh[nt], acc[mt][nt], 0, 0, 0);
        if (SPLIT) {
            bf16x8 al[MT], bl[NT];
#pragma unroll
            for (int mt = 0; mt < MT; mt++)
                al[mt] = *(const bf16x8*)&Asl[wm * WM + mt * 16 + lr][lq * 8];
#pragma unroll
            for (int nt = 0; nt < NT; nt++)
                bl[nt] = *(const bf16x8*)&Bsl[wn * WN + nt * 16 + lr][lq * 8];
#pragma unroll
            for (int mt = 0; mt < MT; mt++)
#pragma unroll
                for (int nt = 0; nt < NT; nt++) {
                    acc[mt][nt] = __builtin_amdgcn_mfma_f32_16x16x32_bf16(ah[mt], bl[nt], acc[mt][nt], 0, 0, 0);
                    acc[mt][nt] = __builtin_amdgcn_mfma_f32_16x16x32_bf16(al[mt], bh[nt], acc[mt][nt], 0, 0, 0);
                }
        }
        __syncthreads();
    }
#pragma unroll
    for (int mt = 0; mt < MT; mt++)
#pragma unroll
        for (int nt = 0; nt < NT; nt++)
#pragma unroll
            for (int r = 0; r < 4; r++) {
                int m_local = wm * WM + mt * 16 + lq * 4 + r;
                if (m_local >= valid) continue;
                int row = grow0 + m_local;
                int n = n0 + wn * WN + nt * 16 + lr;
                float v = acc[mt][nt][r] * scale;
                if (CMODE == 2)      ((float*)C0)[(size_t)row * ldc + n] = v;
                else if (CMODE == 0) ((bf16*)C0)[(size_t)row * ldc + n] = __float2bfloat16(v);
                else                 atomicAdd(&hout[(size_t)row_token[row] * 1024 + n], v);
            }
}

// ---------------- G = silu(a1)*a3*row_w over compact assignment rows ----------------
template<int SPLIT>
__global__ __launch_bounds__(256) void moe_act_kernel(
    const void* __restrict__ a13, const float* __restrict__ row_w,
    bf16* __restrict__ gh, bf16* __restrict__ gl)
{
    size_t idx = ((size_t)blockIdx.x * 256 + threadIdx.x) * 4;
    int r = (int)(idx >> 10);
    int c = (int)(idx & 1023);
    float wv = row_w[r];
#pragma unroll
    for (int j = 0; j < 4; j++) {
        float a, b;
        if (SPLIT) {
            const float* p = (const float*)a13 + (size_t)r * 2048;
            a = p[c + j]; b = p[1024 + c + j];
        } else {
            const bf16* p = (const bf16*)a13 + (size_t)r * 2048;
            a = __bfloat162float(p[c + j]); b = __bfloat162float(p[1024 + c + j]);
        }
        float sig = 1.f / (1.f + __expf(-a));
        float g = a * sig * b * wv;
        size_t off = (size_t)r * 1024 + c + j;
        if (SPLIT) { bf16 hh, ll; split_bf(g, hh, ll); gh[off] = hh; gl[off] = ll; }
        else gh[off] = __float2bfloat16(g);
    }
}

extern "C" void kernel_launch(void* const* d_in, const int* in_sizes, int n_in,
                              void* d_out, int out_size, void* d_ws, size_t ws_size,
                              hipStream_t stream)
{
    const int*   ids   = (const int*)d_in[0];
    const int*   pos   = (const int*)d_in[1];
    const float* emb   = (const float*)d_in[2];
    const float* ln1   = (const float*)d_in[3];
    const float* Wq    = (const float*)d_in[4];
    const float* Wk    = (const float*)d_in[5];
    const float* Wv    = (const float*)d_in[6];
    const float* Wo    = (const float*)d_in[7];
    const float* ln2   = (const float*)d_in[8];
    const float* gw    = (const float*)d_in[9];
    const float* w1    = (const float*)d_in[10];
    const float* w3    = (const float*)d_in[11];
    const float* w2    = (const float*)d_in[12];
    const float* normw = (const float*)d_in[13];

    char* p = (char*)d_ws;
    auto alloc = [&](size_t bytes) -> char* {
        char* r = p; p += (bytes + 255) & ~(size_t)255; return r;
    };
    const size_t QKV_E = (size_t)2048 * 1024, WO_E = (size_t)1024 * 1024;
    const size_t W13_E = (size_t)8 * 2048 * 1024, W2_E = (size_t)8 * 1024 * 1024;
    bf16 *qkvtH[L], *wotH[L], *w13tH[L], *w2tH[L];
    for (int l = 0; l < L; l++) {
        qkvtH[l] = (bf16*)alloc(QKV_E * 2);
        wotH[l]  = (bf16*)alloc(WO_E * 2);
        w13tH[l] = (bf16*)alloc(W13_E * 2);
        w2tH[l]  = (bf16*)alloc(W2_E * 2);
    }
    bf16* qkvtL = (bf16*)alloc(QKV_E * 2);
    bf16* wotL  = (bf16*)alloc(WO_E * 2);
    bf16* w13tL = (bf16*)alloc(W13_E * 2);
    bf16* w2tL  = (bf16*)alloc(W2_E * 2);

    float* hbuf = (float*)alloc((size_t)S * H * 4);
    bf16* xh    = (bf16*)alloc((size_t)S * H * 2);
    bf16* xl    = (bf16*)alloc((size_t)S * H * 2);
    bf16* qkvh  = (bf16*)alloc((size_t)S * 2048 * 2);
    bf16* qkvl  = (bf16*)alloc((size_t)S * 2048 * 2);
    bf16* qrb   = (bf16*)alloc((size_t)NH * S * 64 * 2);
    bf16* krb   = (bf16*)alloc((size_t)NKV * S * 64 * 2);
    bf16* vthb  = (bf16*)alloc((size_t)NKV * 64 * S * 2);
    bf16* vtlb  = (bf16*)alloc((size_t)NKV * 64 * S * 2);
    bf16* ohb   = (bf16*)alloc((size_t)S * 1024 * 2);
    bf16* olb   = (bf16*)alloc((size_t)S * 1024 * 2);
    float* a13f = (float*)alloc((size_t)NASSIGN * 2048 * 4);   // reused as bf16 for l1
    bf16* ghb   = (bf16*)alloc((size_t)NASSIGN * 1024 * 2);
    bf16* glb   = (bf16*)alloc((size_t)NASSIGN * 1024 * 2);
    int*   top_idx  = (int*)alloc(NASSIGN * 4);
    float* top_wv   = (float*)alloc(NASSIGN * 4);
    int*   row_token = (int*)alloc(NASSIGN * 4);
    float* row_wv    = (float*)alloc(NASSIGN * 4);
    int4*  desc      = (int4*)alloc((MAXBLK + 1) * 16);

    // ---- weight transpose+convert: layer 0 split, layer 1 plain ----
    for (int l = 0; l < L; l++) {
        const float* wq_l = Wq + (size_t)l * 1024 * 1024;
        const float* wk_l = Wk + (size_t)l * 1024 * 512;
        const float* wv_l = Wv + (size_t)l * 1024 * 512;
        const float* wo_l = Wo + (size_t)l * 1024 * 1024;
        const float* w1_l = w1 + (size_t)l * 8 * 1024 * 1024;
        const float* w3_l = w3 + (size_t)l * 8 * 1024 * 1024;
        const float* w2_l = w2 + (size_t)l * 8 * 1024 * 1024;
        if (l == 0) {
            transpose_cvt<1><<<dim3(32, 32, 1), 256, 0, stream>>>(wq_l, qkvtH[0], qkvtL, 1024, 0, 0, 1024);
            transpose_cvt<1><<<dim3(16, 32, 1), 256, 0, stream>>>(wk_l, qkvtH[0] + WO_E, qkvtL + WO_E, 512, 0, 0, 1024);
            transpose_cvt<1><<<dim3(16, 32, 1), 256, 0, stream>>>(wv_l, qkvtH[0] + WO_E + WO_E / 2, qkvtL + WO_E + WO_E / 2, 512, 0, 0, 1024);
            transpose_cvt<1><<<dim3(32, 32, 1), 256, 0, stream>>>(wo_l, wotH[0], wotL, 1024, 0, 0, 1024);
            transpose_cvt<1><<<dim3(32, 32, 8), 256, 0, stream>>>(w1_l, w13tH[0], w13tL, 1024, 1024 * 1024, 2048 * 1024, 1024);
            transpose_cvt<1><<<dim3(32, 32, 8), 256, 0, stream>>>(w3_l, w13tH[0] + (size_t)1024 * 1024, w13tL + (size_t)1024 * 1024, 1024, 1024 * 1024, 2048 * 1024, 1024);
            transpose_cvt<1><<<dim3(32, 32, 8), 256, 0, stream>>>(w2_l, w2tH[0], w2tL, 1024, 1024 * 1024, 1024 * 1024, 1024);
        } else {
            transpose_cvt<0><<<dim3(32, 32, 1), 256, 0, stream>>>(wq_l, qkvtH[1], nullptr, 1024, 0, 0, 1024);
            transpose_cvt<0><<<dim3(16, 32, 1), 256, 0, stream>>>(wk_l, qkvtH[1] + WO_E, nullptr, 512, 0, 0, 1024);
            transpose_cvt<0><<<dim3(16, 32, 1), 256, 0, stream>>>(wv_l, qkvtH[1] + WO_E + WO_E / 2, nullptr, 512, 0, 0, 1024);
            transpose_cvt<0><<<dim3(32, 32, 1), 256, 0, stream>>>(wo_l, wotH[1], nullptr, 1024, 0, 0, 1024);
            transpose_cvt<0><<<dim3(32, 32, 8), 256, 0, stream>>>(w1_l, w13tH[1], nullptr, 1024, 1024 * 1024, 2048 * 1024, 1024);
            transpose_cvt<0><<<dim3(32, 32, 8), 256, 0, stream>>>(w3_l, w13tH[1] + (size_t)1024 * 1024, nullptr, 1024, 1024 * 1024, 2048 * 1024, 1024);
            transpose_cvt<0><<<dim3(32, 32, 8), 256, 0, stream>>>(w2_l, w2tH[1], nullptr, 1024, 1024 * 1024, 1024 * 1024, 1024);
        }
    }

    embed_kernel<<<S, 256, 0, stream>>>(ids, emb, hbuf);

    for (int l = 0; l < L; l++) {
        if (l == 0) {
            rmsnorm_kernel<2><<<S, 256, 0, stream>>>(hbuf, ln1, xh, xl, nullptr);
            gemm_bt<128, 128, 1, 1, 1><<<dim3(16, 16), 256, 0, stream>>>(
                xh, xl, qkvtH[0], qkvtL, qkvh, qkvl, 1024, 1024, 2048, 1.0f);
            rope_kernel<1><<<S, 256, 0, stream>>>(qkvh, qkvl, pos, qrb, krb, vthb, vtlb);
            attn_kernel<1><<<dim3(32, 16), 256, 0, stream>>>(qrb, krb, vthb, vtlb, ohb, olb);
            gemm_bt<128, 128, 1, 3, 2><<<dim3(8, 16, 2), 256, 0, stream>>>(
                ohb, olb, wotH[0], wotL, hbuf, nullptr, 1024, 1024, 1024, RES_MULT);

            gate_kernel<<<512, 256, 0, stream>>>(hbuf, ln2, gw, top_idx, top_wv);
            route_build<<<1, 256, 0, stream>>>(top_idx, top_wv, row_token, row_wv, desc);
            rmsnorm_kernel<2><<<S, 256, 0, stream>>>(hbuf, ln2, xh, xl, nullptr);
            moe_gemm<128, 1, 1, 2><<<dim3(16, MAXBLK), 256, 0, stream>>>(
                xh, xl, 1024, w13tH[0], w13tL, 2048 * 1024, 1024,
                row_token, desc, a13f, nullptr, 2048, 1.0f, nullptr);
            moe_act_kernel<1><<<NASSIGN * 1024 / 1024, 256, 0, stream>>>(a13f, row_wv, ghb, glb);
            moe_gemm<128, 1, 0, 4><<<dim3(8, MAXBLK), 256, 0, stream>>>(
                ghb, glb, 1024, w2tH[0], w2tL, 1024 * 1024, 1024,
                row_token, desc, nullptr, nullptr, 1024, RES_MULT, hbuf);
        } else {
            rmsnorm_kernel<1><<<S, 256, 0, stream>>>(hbuf, ln1 + H, xh, nullptr, nullptr);
            gemm_bt<128, 128, 0, 0, 1><<<dim3(16, 16), 256, 0, stream>>>(
                xh, nullptr, qkvtH[1], nullptr, qkvh, nullptr, 1024, 1024, 2048, 1.0f);
            rope_kernel<0><<<S, 256, 0, stream>>>(qkvh, nullptr, pos, qrb, krb, vthb, nullptr);
            attn_kernel<0><<<dim3(32, 16), 256, 0, stream>>>(qrb, krb, vthb, nullptr, ohb, nullptr);
            gemm_bt<128, 128, 0, 3, 2><<<dim3(8, 16, 2), 256, 0, stream>>>(
                ohb, nullptr, wotH[1], nullptr, hbuf, nullptr, 1024, 1024, 1024, RES_MULT);

            gate_kernel<<<512, 256, 0, stream>>>(hbuf, ln2 + H, gw + (size_t)H * 8, top_idx, top_wv);
            route_build<<<1, 256, 0, stream>>>(top_idx, top_wv, row_token, row_wv, desc);
            rmsnorm_kernel<1><<<S, 256, 0, stream>>>(hbuf, ln2 + H, xh, nullptr, nullptr);
            moe_gemm<128, 0, 1, 0><<<dim3(16, MAXBLK), 256, 0, stream>>>(
                xh, nullptr, 1024, w13tH[1], nullptr, 2048 * 1024, 1024,
                row_token, desc, (bf16*)a13f, nullptr, 2048, 1.0f, nullptr);
            moe_act_kernel<0><<<NASSIGN * 1024 / 1024, 256, 0, stream>>>((bf16*)a13f, row_wv, ghb, nullptr);
            moe_gemm<128, 0, 0, 4><<<dim3(8, MAXBLK), 256, 0, stream>>>(
                ghb, nullptr, 1024, w2tH[1], nullptr, 1024 * 1024, 1024,
                row_token, desc, nullptr, nullptr, 1024, RES_MULT, hbuf);
        }
    }

    rmsnorm_kernel<0><<<S, 256, 0, stream>>>(hbuf, normw, nullptr, nullptr, (float*)d_out);
}